// Round 20
// baseline (356.327 us; speedup 1.0000x reference)
//
#include <hip/hip_runtime.h>
#include <hip/hip_bf16.h>

// C = triu( triu(A) @ triu(B) ), N=4096, fp32 in/out.
// Pass 1 (prep): zero strictly-lower 128-tiles of C + convert fp32->bf16 into
// TILED FRAGMENT-ORDER 128x32 subtiles in d_ws + 8KB zero page.
// Pass 2 (main): 256x256 tiles; K split into <=20-step chunks -> 384 blocks.
// 2 buffers x 32KB (64KB LDS) -> TWO blocks/CU: while one block sits in its
// per-step vmcnt(0)+barrier, the co-resident block's waves fill the SIMDs
// (TLP overlap per m97/m114 -- R17-R19 proved intra-block scheduling can't
// fill the gap at 1 block/CU). __launch_bounds__(512,4) pins VGPR<=128 so
// 16 waves/CU fit. L<=2 tiles: direct masked stores. L>=3: bf16 partials
// (353 slots). Pass 3 (reduce): 105 tiles x 16 row-stripes, cpt<=7.

#define NDIM 4096
#define SUBT_B 8192                        // one 128x32 bf16 subtile
#define NSUBT 2112                         // packed subtiles per matrix
#define WS_A ((size_t)NSUBT * SUBT_B)      // 17,301,504
#define WS_TOTAL (2 * WS_A)                // 34,603,008
#define ZOFF WS_TOTAL                      // 8KB zero page
#define POFF (WS_TOTAL + 8192)             // bf16 partial region
#define NSLOT 353                          // split chunk-blocks (L>=3)
#define PART_B 131072                      // 256x256 bf16 partial tile
#define WS_NEED (POFF + (size_t)NSLOT * PART_B)   // 80,879,616 (<=85.2MB ok)
#define NZERO 496                          // strictly-lower 128x128 tiles
#define NMAIN 384
#define NREDT 105                          // split tiles (L>=3)
#define CS 20                              // steps per chunk

typedef __attribute__((ext_vector_type(8))) short short8;
typedef __attribute__((ext_vector_type(4))) float f32x4;

__device__ __forceinline__ unsigned pkbf(float a, float b) {
    __hip_bfloat162 h = __float22bfloat162_rn(make_float2(a, b));
    unsigned r;
    __builtin_memcpy(&r, &h, sizeof(r));
    return r;
}

__device__ __forceinline__ float bf2f(unsigned short us) {
    const unsigned u = ((unsigned)us) << 16;
    float f;
    __builtin_memcpy(&f, &u, 4);
    return f;
}

__device__ __forceinline__ void gll16(const void* g, void* l) {
    __builtin_amdgcn_global_load_lds(
        (const __attribute__((address_space(1))) unsigned int*)g,
        (__attribute__((address_space(3))) unsigned int*)l, 16, 0, 0);
}

__device__ __forceinline__ int offA(int p) { return 130 * p - 2 * p * p; }
__device__ __forceinline__ int offB(int q) { return 2 * q * (q + 1); }

// ---------------- pass 1: zero lower C tiles + convert/tile A,B + zpage -----
__global__ __launch_bounds__(256) void prep_kernel(
    const float* __restrict__ A, const float* __restrict__ B,
    float* __restrict__ C, char* __restrict__ ws) {
    const int t = threadIdx.x;
    int b = blockIdx.x;

    if (b < NZERO) {  // ---- zero one strictly-lower 128x128 tile of C ----
        int r = b, p = 1;
        while (r >= p) { r -= p; ++p; }
        const int bi = p, bj = r;          // bj < bi
        const size_t base = (size_t)bi * 128 * NDIM + (size_t)bj * 128;
        const float4 z = make_float4(0.f, 0.f, 0.f, 0.f);
#pragma unroll
        for (int j = 0; j < 16; ++j) {
            const int f = t + 256 * j;
            *reinterpret_cast<float4*>(
                &C[base + (size_t)(f >> 5) * NDIM + (f & 31) * 4]) = z;
        }
        return;
    }
    b -= NZERO;

    if (b < NSUBT) {  // ---- A subtile: [row][k] fp32 -> [g][row][16B] bf16 ----
        int bi = 0, rem = b;
        while (rem >= 128 - 4 * bi) { rem -= 128 - 4 * bi; ++bi; }
        const int kt32 = 4 * bi + rem;

        __shared__ __align__(16) char lsub[SUBT_B];
        const float* src = A + (size_t)(bi * 128) * NDIM + kt32 * 32;
#pragma unroll
        for (int j = 0; j < 4; ++j) {
            const int s4 = t + 256 * j;
            const int row = s4 >> 3;
            const int kf = (s4 & 7) * 4;
            const float4 v =
                *reinterpret_cast<const float4*>(src + (size_t)row * NDIM + kf);
            uint2 w;
            w.x = pkbf(v.x, v.y);
            w.y = pkbf(v.z, v.w);
            *reinterpret_cast<uint2*>(lsub + (kf >> 3) * 2048 + row * 16 +
                                      (kf & 4) * 2) = w;
        }
        __syncthreads();
        char* dst = ws + (size_t)b * SUBT_B;
#pragma unroll
        for (int j = 0; j < 2; ++j) {
            const int d = t + 256 * j;
            *reinterpret_cast<uint4*>(dst + d * 16) =
                *reinterpret_cast<const uint4*>(lsub + d * 16);
        }
        return;
    }
    b -= NSUBT;

    if (b < NSUBT) {  // ---- B subtile: [k][col] fp32 -> [g][col][16B] bf16 ----
        int bj = 0, rem = b;
        while (rem >= 4 * (bj + 1)) { rem -= 4 * (bj + 1); ++bj; }
        const int kt32 = rem;

        const int c = t & 127;
        const int kq = (t >> 7) * 16;
        const float* src = B + (size_t)(kt32 * 32 + kq) * NDIM + bj * 128 + c;
        float v[16];
#pragma unroll
        for (int i = 0; i < 16; ++i) v[i] = src[(size_t)i * NDIM];

        uint4 w0, w1;
        w0.x = pkbf(v[0], v[1]);   w0.y = pkbf(v[2], v[3]);
        w0.z = pkbf(v[4], v[5]);   w0.w = pkbf(v[6], v[7]);
        w1.x = pkbf(v[8], v[9]);   w1.y = pkbf(v[10], v[11]);
        w1.z = pkbf(v[12], v[13]); w1.w = pkbf(v[14], v[15]);

        char* dst = ws + WS_A + (size_t)b * SUBT_B + c * 16;
        const int g0 = kq >> 3;
        *reinterpret_cast<uint4*>(dst + g0 * 2048) = w0;
        *reinterpret_cast<uint4*>(dst + (g0 + 1) * 2048) = w1;
        return;
    }

    {  // ---- 8KB zero page ----
        uint4* zp = reinterpret_cast<uint4*>(ws + ZOFF);
        const uint4 z = {0u, 0u, 0u, 0u};
        zp[t] = z;
        zp[t + 256] = z;
    }
}

// ---------------- pass 2: 256x256 MFMA GEMM, chunked K, 2 blocks/CU --------
__global__ __launch_bounds__(512, 4) void trimm256_kernel(
    const char* __restrict__ ws, float* __restrict__ C,
    char* __restrict__ part) {
    const int tid = threadIdx.x;

    // decode (L desc, bi asc, ch asc): split chunks (L>=3) are ids 0..352
    int bi, bj, ch, cpt;
    {
        int r = blockIdx.x;
        int L = 16;
        for (;; --L) {
            cpt = (8 * L + CS - 1) / CS;
            const int cnt = (17 - L) * cpt;
            if (r < cnt) { bi = r / cpt; ch = r % cpt; break; }
            r -= cnt;
        }
        bj = bi + L - 1;
    }

    const int row0 = bi * 256;
    const int col0 = bj * 256;
    const int ntt = 8 * (bj - bi + 1);           // total steps for the tile
    const int g0 = ch * CS;
    const int nt = min(CS, ntt - g0);            // 4..20 steps this chunk
    const bool direct = (cpt == 1);

    // subtile streams indexed by GLOBAL step g; zero page at triu edges
    const char* srcA0 = ws + (size_t)(offA(2 * bi)) * SUBT_B;
    const char* srcA1 = ws + (size_t)(offA(2 * bi + 1) - 4) * SUBT_B;
    const char* srcB0 = ws + WS_A + (size_t)(offB(2 * bj) + 8 * bi) * SUBT_B;
    const char* srcB1 = ws + WS_A + (size_t)(offB(2 * bj + 1) + 8 * bi) * SUBT_B;
    const char* zpage = ws + ZOFF;

    __shared__ __align__(16) char lds[2][4][SUBT_B];   // 64 KB -> 2 blocks/CU

    f32x4 acc[8][4];
    const f32x4 fz = {0.f, 0.f, 0.f, 0.f};
#pragma unroll
    for (int m = 0; m < 8; ++m)
#pragma unroll
        for (int n = 0; n < 4; ++n) acc[m][n] = fz;

    const int wv = tid >> 6;            // 0..7
    const int wvM = wv >> 2;            // 0..1: row half
    const int wvN = wv & 3;             // 0..3: col quarter
    const int lane = tid & 63;
    const int fr = lane & 15;
    const int gof = (lane >> 4) * 2048;
    const int cbase = (wvN & 1) * 64;
    const int lo = wv * 1024 + lane * 16;

    auto stage = [&](int buf, int g) {  // 4 gll16 per thread
        const char* s0 = srcA0 + (size_t)g * SUBT_B;
        const char* s1 = (g >= 4) ? srcA1 + (size_t)g * SUBT_B : zpage;
        const char* s2 = (g < ntt - 4) ? srcB0 + (size_t)g * SUBT_B : zpage;
        const char* s3 = srcB1 + (size_t)g * SUBT_B;
        char* d = &lds[buf][0][0] + wv * 1024;
        gll16(s0 + lo, d);
        gll16(s1 + lo, d + SUBT_B);
        gll16(s2 + lo, d + 2 * SUBT_B);
        gll16(s3 + lo, d + 3 * SUBT_B);
    };
    auto compute = [&](int buf) {
        const char* A_ = &lds[buf][wvM][0];
        const char* B_ = &lds[buf][2 + (wvN >> 1)][0];
        short8 af[8], bf[4];
#pragma unroll
        for (int m = 0; m < 8; ++m)
            af[m] = *reinterpret_cast<const short8*>(
                A_ + gof + (m * 16 + fr) * 16);
#pragma unroll
        for (int n = 0; n < 4; ++n)
            bf[n] = *reinterpret_cast<const short8*>(
                B_ + gof + (cbase + n * 16 + fr) * 16);
        __builtin_amdgcn_s_setprio(1);
#pragma unroll
        for (int m = 0; m < 8; ++m)
#pragma unroll
            for (int n = 0; n < 4; ++n)
                acc[m][n] = __builtin_amdgcn_mfma_f32_16x16x32_bf16(
                    af[m], bf[n], acc[m][n], 0, 0, 0);
        __builtin_amdgcn_s_setprio(0);
    };

    // ---- 2x32KB single-step double-buffer (R7/R12-proven); the per-step
    //      sync gap is filled by the co-resident block's waves ----
    stage(0, g0);
    for (int t = 0; t < nt; ++t) {
        asm volatile("s_waitcnt vmcnt(0)" ::: "memory");
        __builtin_amdgcn_s_barrier();
        if (t + 1 < nt) stage((t + 1) & 1, g0 + t + 1);
        compute(t & 1);
    }

    if (direct) {
        // ---- direct masked store (tile may touch the diagonal) ----
#pragma unroll
        for (int m = 0; m < 8; ++m) {
            const int rbase = row0 + wvM * 128 + m * 16 + (lane >> 4) * 4;
#pragma unroll
            for (int n = 0; n < 4; ++n) {
                const int col = col0 + wvN * 64 + n * 16 + fr;
#pragma unroll
                for (int r = 0; r < 4; ++r) {
                    const int row = rbase + r;
                    C[(size_t)row * NDIM + col] =
                        (row <= col) ? acc[m][n][r] : 0.f;
                }
            }
        }
    } else {
        // ---- bf16 partial tile, row-major [256][256], slot = blockIdx ----
        char* po = part + (size_t)blockIdx.x * PART_B;
#pragma unroll
        for (int m = 0; m < 8; ++m) {
            const int rl = wvM * 128 + m * 16 + (lane >> 4) * 4;
#pragma unroll
            for (int n = 0; n < 4; ++n) {
                const int cl = wvN * 64 + n * 16 + fr;
#pragma unroll
                for (int r = 0; r < 4; ++r) {
                    const unsigned short us =
                        (unsigned short)(pkbf(acc[m][n][r], 0.f) & 0xffffu);
                    *reinterpret_cast<unsigned short*>(
                        po + (size_t)((rl + r) * 256 + cl) * 2) = us;
                }
            }
        }
    }
}

// ------- pass 3: sum bf16 partials -> C (105 tiles x 16 stripes) -----------
__global__ __launch_bounds__(256) void reduce_kernel(
    const char* __restrict__ part, float* __restrict__ C) {
    const int t = threadIdx.x;
    const int tile = blockIdx.x >> 4;            // 0..104
    const int stripe = blockIdx.x & 15;          // 16 rows each
    int bi, L, slot0, cpt;
    {
        int r = tile, sbase = 0;
        for (L = 16;; --L) {
            cpt = (8 * L + CS - 1) / CS;
            const int cnt = 17 - L;              // tiles at this L (all split)
            if (r < cnt) { bi = r; slot0 = sbase + r * cpt; break; }
            sbase += cnt * cpt;
            r -= cnt;
        }
    }
    const int bj = bi + L - 1;                   // L>=3 -> strictly upper
    const int row0 = bi * 256;
    const int col0 = bj * 256;

    const char* p0 = part + (size_t)slot0 * PART_B;
#pragma unroll
    for (int j = 0; j < 2; ++j) {
        const int g = stripe * 512 + j * 256 + t;   // 8-elem group 0..8191
        const size_t go = (size_t)g * 16;
        float s[8];
#pragma unroll
        for (int k = 0; k < 8; ++k) s[k] = 0.f;
        for (int c = 0; c < cpt; ++c) {          // cpt in {2..7}, uniform
            const short8 v = *reinterpret_cast<const short8*>(
                p0 + (size_t)c * PART_B + go);
#pragma unroll
            for (int k = 0; k < 8; ++k) s[k] += bf2f((unsigned short)v[k]);
        }
        const int rr = g >> 5;                   // 32 groups per 256-col row
        const int cc = (g & 31) * 8;
        float* dst = &C[(size_t)(row0 + rr) * NDIM + col0 + cc];
        *reinterpret_cast<f32x4*>(dst) = *reinterpret_cast<const f32x4*>(&s[0]);
        *reinterpret_cast<f32x4*>(dst + 4) =
            *reinterpret_cast<const f32x4*>(&s[4]);
    }
}

// ---------------- fallback (proven R3 kernel, no workspace) ----------------
#define FLSTR 80
#define NBLK 32
__device__ __forceinline__ int floff(int row, int kb) { return row * FLSTR + kb; }

__global__ __launch_bounds__(256) void trimm_fallback_kernel(
    const float* __restrict__ A, const float* __restrict__ B,
    float* __restrict__ C) {
    const int tid = threadIdx.x;
    const int id = blockIdx.x;
    int bi, bj;
    if (id >= 528) {
        int r = id - 528;
        int p = 1;
        while (r >= p) { r -= p; ++p; }
        bi = p; bj = r;
        const size_t base = (size_t)bi * 128 * NDIM + (size_t)bj * 128;
        const float4 z = make_float4(0.f, 0.f, 0.f, 0.f);
#pragma unroll
        for (int t = 0; t < 16; ++t) {
            const int f = tid + 256 * t;
            *reinterpret_cast<float4*>(
                &C[base + (size_t)(f >> 5) * NDIM + (f & 31) * 4]) = z;
        }
        return;
    }
    {
        int r = id, L = NBLK;
        while (r >= NBLK + 1 - L) { r -= NBLK + 1 - L; --L; }
        bi = r; bj = bi + L - 1;
    }
    const int row0 = bi * 128, col0 = bj * 128;
    __shared__ __align__(16) char lAs[128 * FLSTR];
    __shared__ __align__(16) char lBs[128 * FLSTR];
    f32x4 acc[4][4];
    const f32x4 fz = {0.f, 0.f, 0.f, 0.f};
#pragma unroll
    for (int m = 0; m < 4; ++m)
#pragma unroll
        for (int n = 0; n < 4; ++n) acc[m][n] = fz;
    const int wv = tid >> 6, wr = (wv >> 1) * 64, wc = (wv & 1) * 64;
    const int lane = tid & 63, fr = lane & 15, kb = (lane >> 4) * 16;
    const int bn = tid & 127, bkh = (tid >> 7) * 16;
    const int kendf = col0 + 128;
    for (int kt = row0; kt < kendf; kt += 32) {
        __syncthreads();
#pragma unroll
        for (int j = 0; j < 4; ++j) {
            const int f = tid + 256 * j;
            const int rr = f >> 3, kq = (f & 7) * 4;
            const float4 v = *reinterpret_cast<const float4*>(
                &A[(size_t)(row0 + rr) * NDIM + kt + kq]);
            uint2 w;
            w.x = pkbf(v.x, v.y); w.y = pkbf(v.z, v.w);
            *reinterpret_cast<uint2*>(lAs + floff(rr, kq * 2)) = w;
        }
        {
            float tv[16];
#pragma unroll
            for (int kk = 0; kk < 16; ++kk)
                tv[kk] = B[(size_t)(kt + bkh + kk) * NDIM + col0 + bn];
            uint4 w0, w1;
            w0.x = pkbf(tv[0], tv[1]);   w0.y = pkbf(tv[2], tv[3]);
            w0.z = pkbf(tv[4], tv[5]);   w0.w = pkbf(tv[6], tv[7]);
            w1.x = pkbf(tv[8], tv[9]);   w1.y = pkbf(tv[10], tv[11]);
            w1.z = pkbf(tv[12], tv[13]); w1.w = pkbf(tv[14], tv[15]);
            *reinterpret_cast<uint4*>(lBs + floff(bn, bkh * 2)) = w0;
            *reinterpret_cast<uint4*>(lBs + floff(bn, bkh * 2 + 16)) = w1;
        }
        __syncthreads();
        short8 af[4], bf[4];
#pragma unroll
        for (int m = 0; m < 4; ++m)
            af[m] = *reinterpret_cast<const short8*>(
                lAs + floff(wr + m * 16 + fr, kb));
#pragma unroll
        for (int n = 0; n < 4; ++n)
            bf[n] = *reinterpret_cast<const short8*>(
                lBs + floff(wc + n * 16 + fr, kb));
#pragma unroll
        for (int m = 0; m < 4; ++m)
#pragma unroll
            for (int n = 0; n < 4; ++n)
                acc[m][n] = __builtin_amdgcn_mfma_f32_16x16x32_bf16(
                    af[m], bf[n], acc[m][n], 0, 0, 0);
    }
#pragma unroll
    for (int m = 0; m < 4; ++m) {
        const int rbase = row0 + wr + m * 16 + (lane >> 4) * 4;
#pragma unroll
        for (int n = 0; n < 4; ++n) {
            const int col = col0 + wc + n * 16 + fr;
#pragma unroll
            for (int r = 0; r < 4; ++r) {
                const int row = rbase + r;
                C[(size_t)row * NDIM + col] = (row <= col) ? acc[m][n][r] : 0.f;
            }
        }
    }
}

extern "C" void kernel_launch(void* const* d_in, const int* in_sizes, int n_in,
                              void* d_out, int out_size, void* d_ws,
                              size_t ws_size, hipStream_t stream) {
    const float* A = (const float*)d_in[0];
    const float* B = (const float*)d_in[1];
    float* C = (float*)d_out;
    if (ws_size >= WS_NEED) {
        char* ws = (char*)d_ws;
        char* part = ws + POFF;
        prep_kernel<<<dim3(NZERO + 2 * NSUBT + 1), dim3(256), 0, stream>>>(
            A, B, C, ws);
        trimm256_kernel<<<dim3(NMAIN), dim3(512), 0, stream>>>(ws, C, part);
        reduce_kernel<<<dim3(NREDT * 16), dim3(256), 0, stream>>>(part, C);
    } else {
        trimm_fallback_kernel<<<dim3(1024), dim3(256), 0, stream>>>(A, B, C);
    }
}

// Round 21
// 66.437 us; speedup vs baseline: 5.3634x; 5.3634x over previous
//
#include <hip/hip_runtime.h>
#include <hip/hip_bf16.h>

// C = triu( triu(A) @ triu(B) ), N=4096, fp32 in/out.
// Pass 1 (prep): zero strictly-lower 128-tiles of C + convert fp32->bf16 into
// TILED FRAGMENT-ORDER 128x32 subtiles in d_ws + 8KB zero page.
// Pass 2 (main): 256x256 tiles; K split into <=36-step chunks -> 248 blocks,
// now 1024 threads = 16 waves (4x4 wave grid, 64x64 per wave, acc[4][4]) ->
// 4 waves/SIMD at 1 block/CU: cross-wave TLP fills the per-step sync gap
// (R17-R19 proved intra-wave scheduling cannot; R20's 2-block attempt
// spilled - acc[8][4]+VGPR cap). 2 buffers x 32KB, vmcnt(0)+barrier per
// step. L<=4 tiles: direct masked stores. L>=5: bf16 partials.
// Pass 3 (reduce): 78 tiles x 16 row-stripes = 1248 blocks.

#define NDIM 4096
#define SUBT_B 8192                        // one 128x32 bf16 subtile
#define NSUBT 2112                         // packed subtiles per matrix
#define WS_A ((size_t)NSUBT * SUBT_B)      // 17,301,504
#define WS_TOTAL (2 * WS_A)                // 34,603,008
#define ZOFF WS_TOTAL                      // 8KB zero page
#define POFF (WS_TOTAL + 8192)             // bf16 partial region
#define NSLOT 190                          // split chunk-blocks
#define PART_B 131072                      // 256x256 bf16 partial tile
#define WS_NEED (POFF + (size_t)NSLOT * PART_B)   // 59,514,880
#define NZERO 496                          // strictly-lower 128x128 tiles
#define NMAIN 248
#define NRED 78
#define CS 36                              // steps per chunk (even)

typedef __attribute__((ext_vector_type(8))) short short8;
typedef __attribute__((ext_vector_type(4))) float f32x4;

__device__ __forceinline__ unsigned pkbf(float a, float b) {
    __hip_bfloat162 h = __float22bfloat162_rn(make_float2(a, b));
    unsigned r;
    __builtin_memcpy(&r, &h, sizeof(r));
    return r;
}

__device__ __forceinline__ float bf2f(unsigned short us) {
    const unsigned u = ((unsigned)us) << 16;
    float f;
    __builtin_memcpy(&f, &u, 4);
    return f;
}

__device__ __forceinline__ void gll16(const void* g, void* l) {
    __builtin_amdgcn_global_load_lds(
        (const __attribute__((address_space(1))) unsigned int*)g,
        (__attribute__((address_space(3))) unsigned int*)l, 16, 0, 0);
}

__device__ __forceinline__ int offA(int p) { return 130 * p - 2 * p * p; }
__device__ __forceinline__ int offB(int q) { return 2 * q * (q + 1); }

// ---------------- pass 1: zero lower C tiles + convert/tile A,B + zpage -----
__global__ __launch_bounds__(256) void prep_kernel(
    const float* __restrict__ A, const float* __restrict__ B,
    float* __restrict__ C, char* __restrict__ ws) {
    const int t = threadIdx.x;
    int b = blockIdx.x;

    if (b < NZERO) {  // ---- zero one strictly-lower 128x128 tile of C ----
        int r = b, p = 1;
        while (r >= p) { r -= p; ++p; }
        const int bi = p, bj = r;          // bj < bi
        const size_t base = (size_t)bi * 128 * NDIM + (size_t)bj * 128;
        const float4 z = make_float4(0.f, 0.f, 0.f, 0.f);
#pragma unroll
        for (int j = 0; j < 16; ++j) {
            const int f = t + 256 * j;
            *reinterpret_cast<float4*>(
                &C[base + (size_t)(f >> 5) * NDIM + (f & 31) * 4]) = z;
        }
        return;
    }
    b -= NZERO;

    if (b < NSUBT) {  // ---- A subtile: [row][k] fp32 -> [g][row][16B] bf16 ----
        int bi = 0, rem = b;
        while (rem >= 128 - 4 * bi) { rem -= 128 - 4 * bi; ++bi; }
        const int kt32 = 4 * bi + rem;

        __shared__ __align__(16) char lsub[SUBT_B];
        const float* src = A + (size_t)(bi * 128) * NDIM + kt32 * 32;
#pragma unroll
        for (int j = 0; j < 4; ++j) {
            const int s4 = t + 256 * j;
            const int row = s4 >> 3;
            const int kf = (s4 & 7) * 4;
            const float4 v =
                *reinterpret_cast<const float4*>(src + (size_t)row * NDIM + kf);
            uint2 w;
            w.x = pkbf(v.x, v.y);
            w.y = pkbf(v.z, v.w);
            *reinterpret_cast<uint2*>(lsub + (kf >> 3) * 2048 + row * 16 +
                                      (kf & 4) * 2) = w;
        }
        __syncthreads();
        char* dst = ws + (size_t)b * SUBT_B;
#pragma unroll
        for (int j = 0; j < 2; ++j) {
            const int d = t + 256 * j;
            *reinterpret_cast<uint4*>(dst + d * 16) =
                *reinterpret_cast<const uint4*>(lsub + d * 16);
        }
        return;
    }
    b -= NSUBT;

    if (b < NSUBT) {  // ---- B subtile: [k][col] fp32 -> [g][col][16B] bf16 ----
        int bj = 0, rem = b;
        while (rem >= 4 * (bj + 1)) { rem -= 4 * (bj + 1); ++bj; }
        const int kt32 = rem;

        const int c = t & 127;
        const int kq = (t >> 7) * 16;
        const float* src = B + (size_t)(kt32 * 32 + kq) * NDIM + bj * 128 + c;
        float v[16];
#pragma unroll
        for (int i = 0; i < 16; ++i) v[i] = src[(size_t)i * NDIM];

        uint4 w0, w1;
        w0.x = pkbf(v[0], v[1]);   w0.y = pkbf(v[2], v[3]);
        w0.z = pkbf(v[4], v[5]);   w0.w = pkbf(v[6], v[7]);
        w1.x = pkbf(v[8], v[9]);   w1.y = pkbf(v[10], v[11]);
        w1.z = pkbf(v[12], v[13]); w1.w = pkbf(v[14], v[15]);

        char* dst = ws + WS_A + (size_t)b * SUBT_B + c * 16;
        const int g0 = kq >> 3;
        *reinterpret_cast<uint4*>(dst + g0 * 2048) = w0;
        *reinterpret_cast<uint4*>(dst + (g0 + 1) * 2048) = w1;
        return;
    }

    {  // ---- 8KB zero page ----
        uint4* zp = reinterpret_cast<uint4*>(ws + ZOFF);
        const uint4 z = {0u, 0u, 0u, 0u};
        zp[t] = z;
        zp[t + 256] = z;
    }
}

// ------- pass 2: 256x256 MFMA GEMM, 16 waves (4 waves/SIMD TLP) ------------
__global__ __launch_bounds__(1024) void trimm256_kernel(
    const char* __restrict__ ws, float* __restrict__ C,
    char* __restrict__ part) {
    const int tid = threadIdx.x;

    // decode (L desc, bi asc, ch asc): split chunks (L>=5) are ids 0..189
    int bi, bj, ch, cpt;
    {
        int r = blockIdx.x;
        int L = 16;
        for (;; --L) {
            cpt = (8 * L + CS - 1) / CS;
            const int cnt = (17 - L) * cpt;
            if (r < cnt) { bi = r / cpt; ch = r % cpt; break; }
            r -= cnt;
        }
        bj = bi + L - 1;
    }

    const int row0 = bi * 256;
    const int col0 = bj * 256;
    const int ntt = 8 * (bj - bi + 1);           // total steps for the tile
    const int g0 = ch * CS;
    const int nt = min(CS, ntt - g0);            // 4..36 steps this chunk
    const bool direct = (cpt == 1);

    // subtile streams indexed by GLOBAL step g; zero page at triu edges
    const char* srcA0 = ws + (size_t)(offA(2 * bi)) * SUBT_B;
    const char* srcA1 = ws + (size_t)(offA(2 * bi + 1) - 4) * SUBT_B;
    const char* srcB0 = ws + WS_A + (size_t)(offB(2 * bj) + 8 * bi) * SUBT_B;
    const char* srcB1 = ws + WS_A + (size_t)(offB(2 * bj + 1) + 8 * bi) * SUBT_B;
    const char* zpage = ws + ZOFF;

    __shared__ __align__(16) char lds[2][4][SUBT_B];   // 64 KB

    f32x4 acc[4][4];
    const f32x4 fz = {0.f, 0.f, 0.f, 0.f};
#pragma unroll
    for (int m = 0; m < 4; ++m)
#pragma unroll
        for (int n = 0; n < 4; ++n) acc[m][n] = fz;

    const int wv = tid >> 6;            // 0..15
    const int wvM = wv >> 2;            // 0..3: 64-row band
    const int wvN = wv & 3;             // 0..3: 64-col band
    const int lane = tid & 63;
    const int fr = lane & 15;
    const int gof = (lane >> 4) * 2048;
    const int arb = (wvM & 1) * 64;     // row base within A subtile
    const int cbase = (wvN & 1) * 64;   // col base within B subtile
    const int soff = (wv & 7) * 1024;   // staging slice offset

    auto stage = [&](int buf, int g) {  // 2 gll16 per thread
#pragma unroll
        for (int q = 0; q < 2; ++q) {
            const int s = q * 2 + (wv >> 3);     // wave-uniform subtile id
            const char* src;
            if (s == 0)      src = srcA0 + (size_t)g * SUBT_B;
            else if (s == 1) src = (g >= 4) ? srcA1 + (size_t)g * SUBT_B : zpage;
            else if (s == 2) src = (g < ntt - 4) ? srcB0 + (size_t)g * SUBT_B : zpage;
            else             src = srcB1 + (size_t)g * SUBT_B;
            gll16(src + soff + lane * 16, &lds[buf][s][0] + soff);
        }
    };
    auto compute = [&](int buf) {
        const char* A_ = &lds[buf][wvM >> 1][0];
        const char* B_ = &lds[buf][2 + (wvN >> 1)][0];
        short8 af[4], bf[4];
#pragma unroll
        for (int m = 0; m < 4; ++m)
            af[m] = *reinterpret_cast<const short8*>(
                A_ + gof + (arb + m * 16 + fr) * 16);
#pragma unroll
        for (int n = 0; n < 4; ++n)
            bf[n] = *reinterpret_cast<const short8*>(
                B_ + gof + (cbase + n * 16 + fr) * 16);
        __builtin_amdgcn_s_setprio(1);
#pragma unroll
        for (int m = 0; m < 4; ++m)
#pragma unroll
            for (int n = 0; n < 4; ++n)
                acc[m][n] = __builtin_amdgcn_mfma_f32_16x16x32_bf16(
                    af[m], bf[n], acc[m][n], 0, 0, 0);
        __builtin_amdgcn_s_setprio(0);
    };

    // ---- 2x32KB single-step double-buffer; cross-wave TLP fills the gap ----
    stage(0, g0);
    for (int t = 0; t < nt; ++t) {
        asm volatile("s_waitcnt vmcnt(0)" ::: "memory");
        __builtin_amdgcn_s_barrier();
        if (t + 1 < nt) stage((t + 1) & 1, g0 + t + 1);
        compute(t & 1);
    }

    if (direct) {
        // ---- direct masked store (tile may touch the diagonal) ----
#pragma unroll
        for (int m = 0; m < 4; ++m) {
            const int rbase = row0 + wvM * 64 + m * 16 + (lane >> 4) * 4;
#pragma unroll
            for (int n = 0; n < 4; ++n) {
                const int col = col0 + wvN * 64 + n * 16 + fr;
#pragma unroll
                for (int r = 0; r < 4; ++r) {
                    const int row = rbase + r;
                    C[(size_t)row * NDIM + col] =
                        (row <= col) ? acc[m][n][r] : 0.f;
                }
            }
        }
    } else {
        // ---- bf16 partial tile, row-major [256][256], slot = blockIdx ----
        char* po = part + (size_t)blockIdx.x * PART_B;
#pragma unroll
        for (int m = 0; m < 4; ++m) {
            const int rl = wvM * 64 + m * 16 + (lane >> 4) * 4;
#pragma unroll
            for (int n = 0; n < 4; ++n) {
                const int cl = wvN * 64 + n * 16 + fr;
#pragma unroll
                for (int r = 0; r < 4; ++r) {
                    const unsigned short us =
                        (unsigned short)(pkbf(acc[m][n][r], 0.f) & 0xffffu);
                    *reinterpret_cast<unsigned short*>(
                        po + (size_t)((rl + r) * 256 + cl) * 2) = us;
                }
            }
        }
    }
}

// ------- pass 3: sum bf16 partials -> C (78 tiles x 16 stripes) ------------
__global__ __launch_bounds__(256) void reduce_kernel(
    const char* __restrict__ part, float* __restrict__ C) {
    const int t = threadIdx.x;
    const int tile = blockIdx.x >> 4;            // 0..77
    const int stripe = blockIdx.x & 15;          // 16 rows each
    int bi, L, slot0, cpt;
    {
        int r = tile, sbase = 0;
        for (L = 16;; --L) {
            cpt = (8 * L + CS - 1) / CS;
            const int cnt = 17 - L;              // tiles at this L (all split)
            if (r < cnt) { bi = r; slot0 = sbase + r * cpt; break; }
            sbase += cnt * cpt;
            r -= cnt;
        }
    }
    const int bj = bi + L - 1;                   // L>=5 -> strictly upper
    const int row0 = bi * 256;
    const int col0 = bj * 256;

    const char* p0 = part + (size_t)slot0 * PART_B;
#pragma unroll
    for (int j = 0; j < 2; ++j) {
        const int g = stripe * 512 + j * 256 + t;   // 8-elem group 0..8191
        const size_t go = (size_t)g * 16;
        float s[8];
        const short8 v0 = *reinterpret_cast<const short8*>(p0 + go);
        const short8 v1 = *reinterpret_cast<const short8*>(p0 + PART_B + go);
#pragma unroll
        for (int k = 0; k < 8; ++k)
            s[k] = bf2f((unsigned short)v0[k]) + bf2f((unsigned short)v1[k]);
        if (cpt > 2) {
            const short8 v2 =
                *reinterpret_cast<const short8*>(p0 + 2 * PART_B + go);
#pragma unroll
            for (int k = 0; k < 8; ++k) s[k] += bf2f((unsigned short)v2[k]);
        }
        if (cpt > 3) {
            const short8 v3 =
                *reinterpret_cast<const short8*>(p0 + 3 * PART_B + go);
#pragma unroll
            for (int k = 0; k < 8; ++k) s[k] += bf2f((unsigned short)v3[k]);
        }
        const int rr = g >> 5;                   // 32 groups per 256-col row
        const int cc = (g & 31) * 8;
        float* dst = &C[(size_t)(row0 + rr) * NDIM + col0 + cc];
        *reinterpret_cast<f32x4*>(dst) = *reinterpret_cast<const f32x4*>(&s[0]);
        *reinterpret_cast<f32x4*>(dst + 4) =
            *reinterpret_cast<const f32x4*>(&s[4]);
    }
}

// ---------------- fallback (proven R3 kernel, no workspace) ----------------
#define FLSTR 80
#define NBLK 32
__device__ __forceinline__ int floff(int row, int kb) { return row * FLSTR + kb; }

__global__ __launch_bounds__(256) void trimm_fallback_kernel(
    const float* __restrict__ A, const float* __restrict__ B,
    float* __restrict__ C) {
    const int tid = threadIdx.x;
    const int id = blockIdx.x;
    int bi, bj;
    if (id >= 528) {
        int r = id - 528;
        int p = 1;
        while (r >= p) { r -= p; ++p; }
        bi = p; bj = r;
        const size_t base = (size_t)bi * 128 * NDIM + (size_t)bj * 128;
        const float4 z = make_float4(0.f, 0.f, 0.f, 0.f);
#pragma unroll
        for (int t = 0; t < 16; ++t) {
            const int f = tid + 256 * t;
            *reinterpret_cast<float4*>(
                &C[base + (size_t)(f >> 5) * NDIM + (f & 31) * 4]) = z;
        }
        return;
    }
    {
        int r = id, L = NBLK;
        while (r >= NBLK + 1 - L) { r -= NBLK + 1 - L; --L; }
        bi = r; bj = bi + L - 1;
    }
    const int row0 = bi * 128, col0 = bj * 128;
    __shared__ __align__(16) char lAs[128 * FLSTR];
    __shared__ __align__(16) char lBs[128 * FLSTR];
    f32x4 acc[4][4];
    const f32x4 fz = {0.f, 0.f, 0.f, 0.f};
#pragma unroll
    for (int m = 0; m < 4; ++m)
#pragma unroll
        for (int n = 0; n < 4; ++n) acc[m][n] = fz;
    const int wv = tid >> 6, wr = (wv >> 1) * 64, wc = (wv & 1) * 64;
    const int lane = tid & 63, fr = lane & 15, kb = (lane >> 4) * 16;
    const int bn = tid & 127, bkh = (tid >> 7) * 16;
    const int kendf = col0 + 128;
    for (int kt = row0; kt < kendf; kt += 32) {
        __syncthreads();
#pragma unroll
        for (int j = 0; j < 4; ++j) {
            const int f = tid + 256 * j;
            const int rr = f >> 3, kq = (f & 7) * 4;
            const float4 v = *reinterpret_cast<const float4*>(
                &A[(size_t)(row0 + rr) * NDIM + kt + kq]);
            uint2 w;
            w.x = pkbf(v.x, v.y); w.y = pkbf(v.z, v.w);
            *reinterpret_cast<uint2*>(lAs + floff(rr, kq * 2)) = w;
        }
        {
            float tv[16];
#pragma unroll
            for (int kk = 0; kk < 16; ++kk)
                tv[kk] = B[(size_t)(kt + bkh + kk) * NDIM + col0 + bn];
            uint4 w0, w1;
            w0.x = pkbf(tv[0], tv[1]);   w0.y = pkbf(tv[2], tv[3]);
            w0.z = pkbf(tv[4], tv[5]);   w0.w = pkbf(tv[6], tv[7]);
            w1.x = pkbf(tv[8], tv[9]);   w1.y = pkbf(tv[10], tv[11]);
            w1.z = pkbf(tv[12], tv[13]); w1.w = pkbf(tv[14], tv[15]);
            *reinterpret_cast<uint4*>(lBs + floff(bn, bkh * 2)) = w0;
            *reinterpret_cast<uint4*>(lBs + floff(bn, bkh * 2 + 16)) = w1;
        }
        __syncthreads();
        short8 af[4], bf[4];
#pragma unroll
        for (int m = 0; m < 4; ++m)
            af[m] = *reinterpret_cast<const short8*>(
                lAs + floff(wr + m * 16 + fr, kb));
#pragma unroll
        for (int n = 0; n < 4; ++n)
            bf[n] = *reinterpret_cast<const short8*>(
                lBs + floff(wc + n * 16 + fr, kb));
#pragma unroll
        for (int m = 0; m < 4; ++m)
#pragma unroll
            for (int n = 0; n < 4; ++n)
                acc[m][n] = __builtin_amdgcn_mfma_f32_16x16x32_bf16(
                    af[m], bf[n], acc[m][n], 0, 0, 0);
    }
#pragma unroll
    for (int m = 0; m < 4; ++m) {
        const int rbase = row0 + wr + m * 16 + (lane >> 4) * 4;
#pragma unroll
        for (int n = 0; n < 4; ++n) {
            const int col = col0 + wc + n * 16 + fr;
#pragma unroll
            for (int r = 0; r < 4; ++r) {
                const int row = rbase + r;
                C[(size_t)row * NDIM + col] = (row <= col) ? acc[m][n][r] : 0.f;
            }
        }
    }
}

extern "C" void kernel_launch(void* const* d_in, const int* in_sizes, int n_in,
                              void* d_out, int out_size, void* d_ws,
                              size_t ws_size, hipStream_t stream) {
    const float* A = (const float*)d_in[0];
    const float* B = (const float*)d_in[1];
    float* C = (float*)d_out;
    if (ws_size >= WS_NEED) {
        char* ws = (char*)d_ws;
        char* part = ws + POFF;
        prep_kernel<<<dim3(NZERO + 2 * NSUBT + 1), dim3(256), 0, stream>>>(
            A, B, C, ws);
        trimm256_kernel<<<dim3(NMAIN), dim3(1024), 0, stream>>>(ws, C, part);
        reduce_kernel<<<dim3(NRED * 16), dim3(256), 0, stream>>>(part, C);
    } else {
        trimm_fallback_kernel<<<dim3(1024), dim3(256), 0, stream>>>(A, B, C);
    }
}

// Round 22
// 63.802 us; speedup vs baseline: 5.5849x; 1.0413x over previous
//
#include <hip/hip_runtime.h>
#include <hip/hip_bf16.h>

// C = triu( triu(A) @ triu(B) ), N=4096, fp32 in/out.
// Pass 1 (prep): convert fp32->bf16 into TILED FRAGMENT-ORDER 128x32 subtiles
// in d_ws + 8KB zero page. (zero-C moved OUT: prep was HBM-bound at exactly
// its traffic; the 31MB of zero writes now ride in main's idle capacity.)
// Pass 2 (main): 256x256 tiles; K split into <=36-step chunks -> 248 GEMM
// blocks (16 waves, 64x64/wave, 2x32KB double buffer, vmcnt(0)+barrier per
// step) + 496 appended blocks that zero the strictly-lower 128-tiles of C.
// L<=4 tiles: direct masked stores. L>=5: bf16 partials.
// Pass 3 (reduce): 78 tiles x 16 row-stripes = 1248 blocks.

#define NDIM 4096
#define SUBT_B 8192                        // one 128x32 bf16 subtile
#define NSUBT 2112                         // packed subtiles per matrix
#define WS_A ((size_t)NSUBT * SUBT_B)      // 17,301,504
#define WS_TOTAL (2 * WS_A)                // 34,603,008
#define ZOFF WS_TOTAL                      // 8KB zero page
#define POFF (WS_TOTAL + 8192)             // bf16 partial region
#define NSLOT 190                          // split chunk-blocks
#define PART_B 131072                      // 256x256 bf16 partial tile
#define WS_NEED (POFF + (size_t)NSLOT * PART_B)   // 59,514,880
#define NZERO 496                          // strictly-lower 128x128 tiles
#define NMAIN 248
#define NRED 78
#define CS 36                              // steps per chunk (even)

typedef __attribute__((ext_vector_type(8))) short short8;
typedef __attribute__((ext_vector_type(4))) float f32x4;

__device__ __forceinline__ unsigned pkbf(float a, float b) {
    __hip_bfloat162 h = __float22bfloat162_rn(make_float2(a, b));
    unsigned r;
    __builtin_memcpy(&r, &h, sizeof(r));
    return r;
}

__device__ __forceinline__ float bf2f(unsigned short us) {
    const unsigned u = ((unsigned)us) << 16;
    float f;
    __builtin_memcpy(&f, &u, 4);
    return f;
}

__device__ __forceinline__ void gll16(const void* g, void* l) {
    __builtin_amdgcn_global_load_lds(
        (const __attribute__((address_space(1))) unsigned int*)g,
        (__attribute__((address_space(3))) unsigned int*)l, 16, 0, 0);
}

__device__ __forceinline__ int offA(int p) { return 130 * p - 2 * p * p; }
__device__ __forceinline__ int offB(int q) { return 2 * q * (q + 1); }

// ---------------- pass 1: convert/tile A,B + zero page ---------------------
__global__ __launch_bounds__(256) void prep_kernel(
    const float* __restrict__ A, const float* __restrict__ B,
    char* __restrict__ ws) {
    const int t = threadIdx.x;
    int b = blockIdx.x;

    if (b < NSUBT) {  // ---- A subtile: [row][k] fp32 -> [g][row][16B] bf16 ----
        int bi = 0, rem = b;
        while (rem >= 128 - 4 * bi) { rem -= 128 - 4 * bi; ++bi; }
        const int kt32 = 4 * bi + rem;

        __shared__ __align__(16) char lsub[SUBT_B];
        const float* src = A + (size_t)(bi * 128) * NDIM + kt32 * 32;
#pragma unroll
        for (int j = 0; j < 4; ++j) {
            const int s4 = t + 256 * j;
            const int row = s4 >> 3;
            const int kf = (s4 & 7) * 4;
            const float4 v =
                *reinterpret_cast<const float4*>(src + (size_t)row * NDIM + kf);
            uint2 w;
            w.x = pkbf(v.x, v.y);
            w.y = pkbf(v.z, v.w);
            *reinterpret_cast<uint2*>(lsub + (kf >> 3) * 2048 + row * 16 +
                                      (kf & 4) * 2) = w;
        }
        __syncthreads();
        char* dst = ws + (size_t)b * SUBT_B;
#pragma unroll
        for (int j = 0; j < 2; ++j) {
            const int d = t + 256 * j;
            *reinterpret_cast<uint4*>(dst + d * 16) =
                *reinterpret_cast<const uint4*>(lsub + d * 16);
        }
        return;
    }
    b -= NSUBT;

    if (b < NSUBT) {  // ---- B subtile: [k][col] fp32 -> [g][col][16B] bf16 ----
        int bj = 0, rem = b;
        while (rem >= 4 * (bj + 1)) { rem -= 4 * (bj + 1); ++bj; }
        const int kt32 = rem;

        const int c = t & 127;
        const int kq = (t >> 7) * 16;
        const float* src = B + (size_t)(kt32 * 32 + kq) * NDIM + bj * 128 + c;
        float v[16];
#pragma unroll
        for (int i = 0; i < 16; ++i) v[i] = src[(size_t)i * NDIM];

        uint4 w0, w1;
        w0.x = pkbf(v[0], v[1]);   w0.y = pkbf(v[2], v[3]);
        w0.z = pkbf(v[4], v[5]);   w0.w = pkbf(v[6], v[7]);
        w1.x = pkbf(v[8], v[9]);   w1.y = pkbf(v[10], v[11]);
        w1.z = pkbf(v[12], v[13]); w1.w = pkbf(v[14], v[15]);

        char* dst = ws + WS_A + (size_t)b * SUBT_B + c * 16;
        const int g0 = kq >> 3;
        *reinterpret_cast<uint4*>(dst + g0 * 2048) = w0;
        *reinterpret_cast<uint4*>(dst + (g0 + 1) * 2048) = w1;
        return;
    }

    {  // ---- 8KB zero page ----
        uint4* zp = reinterpret_cast<uint4*>(ws + ZOFF);
        const uint4 z = {0u, 0u, 0u, 0u};
        zp[t] = z;
        zp[t + 256] = z;
    }
}

// ------- pass 2: 256x256 MFMA GEMM (16 waves) + lower-tile zero blocks -----
__global__ __launch_bounds__(1024) void trimm256_kernel(
    const char* __restrict__ ws, float* __restrict__ C,
    char* __restrict__ part) {
    const int tid = threadIdx.x;

    if (blockIdx.x >= NMAIN) {
        // ---- zero one strictly-lower 128x128 tile of C ----
        int r = blockIdx.x - NMAIN, p = 1;
        while (r >= p) { r -= p; ++p; }
        const int zbi = p, zbj = r;        // zbj < zbi
        const size_t base = (size_t)zbi * 128 * NDIM + (size_t)zbj * 128;
        const float4 z = make_float4(0.f, 0.f, 0.f, 0.f);
#pragma unroll
        for (int j = 0; j < 4; ++j) {
            const int f = tid + 1024 * j;  // 0..4095 float4 chunks
            *reinterpret_cast<float4*>(
                &C[base + (size_t)(f >> 5) * NDIM + (f & 31) * 4]) = z;
        }
        return;
    }

    // decode (L desc, bi asc, ch asc): split chunks (L>=5) are ids 0..189
    int bi, bj, ch, cpt;
    {
        int r = blockIdx.x;
        int L = 16;
        for (;; --L) {
            cpt = (8 * L + CS - 1) / CS;
            const int cnt = (17 - L) * cpt;
            if (r < cnt) { bi = r / cpt; ch = r % cpt; break; }
            r -= cnt;
        }
        bj = bi + L - 1;
    }

    const int row0 = bi * 256;
    const int col0 = bj * 256;
    const int ntt = 8 * (bj - bi + 1);           // total steps for the tile
    const int g0 = ch * CS;
    const int nt = min(CS, ntt - g0);            // 4..36 steps this chunk
    const bool direct = (cpt == 1);

    // subtile streams indexed by GLOBAL step g; zero page at triu edges
    const char* srcA0 = ws + (size_t)(offA(2 * bi)) * SUBT_B;
    const char* srcA1 = ws + (size_t)(offA(2 * bi + 1) - 4) * SUBT_B;
    const char* srcB0 = ws + WS_A + (size_t)(offB(2 * bj) + 8 * bi) * SUBT_B;
    const char* srcB1 = ws + WS_A + (size_t)(offB(2 * bj + 1) + 8 * bi) * SUBT_B;
    const char* zpage = ws + ZOFF;

    __shared__ __align__(16) char lds[2][4][SUBT_B];   // 64 KB

    f32x4 acc[4][4];
    const f32x4 fz = {0.f, 0.f, 0.f, 0.f};
#pragma unroll
    for (int m = 0; m < 4; ++m)
#pragma unroll
        for (int n = 0; n < 4; ++n) acc[m][n] = fz;

    const int wv = tid >> 6;            // 0..15
    const int wvM = wv >> 2;            // 0..3: 64-row band
    const int wvN = wv & 3;             // 0..3: 64-col band
    const int lane = tid & 63;
    const int fr = lane & 15;
    const int gof = (lane >> 4) * 2048;
    const int arb = (wvM & 1) * 64;     // row base within A subtile
    const int cbase = (wvN & 1) * 64;   // col base within B subtile
    const int soff = (wv & 7) * 1024;   // staging slice offset

    auto stage = [&](int buf, int g) {  // 2 gll16 per thread
#pragma unroll
        for (int q = 0; q < 2; ++q) {
            const int s = q * 2 + (wv >> 3);     // wave-uniform subtile id
            const char* src;
            if (s == 0)      src = srcA0 + (size_t)g * SUBT_B;
            else if (s == 1) src = (g >= 4) ? srcA1 + (size_t)g * SUBT_B : zpage;
            else if (s == 2) src = (g < ntt - 4) ? srcB0 + (size_t)g * SUBT_B : zpage;
            else             src = srcB1 + (size_t)g * SUBT_B;
            gll16(src + soff + lane * 16, &lds[buf][s][0] + soff);
        }
    };
    auto compute = [&](int buf) {
        const char* A_ = &lds[buf][wvM >> 1][0];
        const char* B_ = &lds[buf][2 + (wvN >> 1)][0];
        short8 af[4], bf[4];
#pragma unroll
        for (int m = 0; m < 4; ++m)
            af[m] = *reinterpret_cast<const short8*>(
                A_ + gof + (arb + m * 16 + fr) * 16);
#pragma unroll
        for (int n = 0; n < 4; ++n)
            bf[n] = *reinterpret_cast<const short8*>(
                B_ + gof + (cbase + n * 16 + fr) * 16);
        __builtin_amdgcn_s_setprio(1);
#pragma unroll
        for (int m = 0; m < 4; ++m)
#pragma unroll
            for (int n = 0; n < 4; ++n)
                acc[m][n] = __builtin_amdgcn_mfma_f32_16x16x32_bf16(
                    af[m], bf[n], acc[m][n], 0, 0, 0);
        __builtin_amdgcn_s_setprio(0);
    };

    // ---- 2x32KB single-step double-buffer ----
    stage(0, g0);
    for (int t = 0; t < nt; ++t) {
        asm volatile("s_waitcnt vmcnt(0)" ::: "memory");
        __builtin_amdgcn_s_barrier();
        if (t + 1 < nt) stage((t + 1) & 1, g0 + t + 1);
        compute(t & 1);
    }

    if (direct) {
        // ---- direct masked store (tile may touch the diagonal) ----
#pragma unroll
        for (int m = 0; m < 4; ++m) {
            const int rbase = row0 + wvM * 64 + m * 16 + (lane >> 4) * 4;
#pragma unroll
            for (int n = 0; n < 4; ++n) {
                const int col = col0 + wvN * 64 + n * 16 + fr;
#pragma unroll
                for (int r = 0; r < 4; ++r) {
                    const int row = rbase + r;
                    C[(size_t)row * NDIM + col] =
                        (row <= col) ? acc[m][n][r] : 0.f;
                }
            }
        }
    } else {
        // ---- bf16 partial tile, row-major [256][256], slot = blockIdx ----
        char* po = part + (size_t)blockIdx.x * PART_B;
#pragma unroll
        for (int m = 0; m < 4; ++m) {
            const int rl = wvM * 64 + m * 16 + (lane >> 4) * 4;
#pragma unroll
            for (int n = 0; n < 4; ++n) {
                const int cl = wvN * 64 + n * 16 + fr;
#pragma unroll
                for (int r = 0; r < 4; ++r) {
                    const unsigned short us =
                        (unsigned short)(pkbf(acc[m][n][r], 0.f) & 0xffffu);
                    *reinterpret_cast<unsigned short*>(
                        po + (size_t)((rl + r) * 256 + cl) * 2) = us;
                }
            }
        }
    }
}

// ------- pass 3: sum bf16 partials -> C (78 tiles x 16 stripes) ------------
__global__ __launch_bounds__(256) void reduce_kernel(
    const char* __restrict__ part, float* __restrict__ C) {
    const int t = threadIdx.x;
    const int tile = blockIdx.x >> 4;            // 0..77
    const int stripe = blockIdx.x & 15;          // 16 rows each
    int bi, L, slot0, cpt;
    {
        int r = tile, sbase = 0;
        for (L = 16;; --L) {
            cpt = (8 * L + CS - 1) / CS;
            const int cnt = 17 - L;              // tiles at this L (all split)
            if (r < cnt) { bi = r; slot0 = sbase + r * cpt; break; }
            sbase += cnt * cpt;
            r -= cnt;
        }
    }
    const int bj = bi + L - 1;                   // L>=5 -> strictly upper
    const int row0 = bi * 256;
    const int col0 = bj * 256;

    const char* p0 = part + (size_t)slot0 * PART_B;
#pragma unroll
    for (int j = 0; j < 2; ++j) {
        const int g = stripe * 512 + j * 256 + t;   // 8-elem group 0..8191
        const size_t go = (size_t)g * 16;
        float s[8];
        const short8 v0 = *reinterpret_cast<const short8*>(p0 + go);
        const short8 v1 = *reinterpret_cast<const short8*>(p0 + PART_B + go);
#pragma unroll
        for (int k = 0; k < 8; ++k)
            s[k] = bf2f((unsigned short)v0[k]) + bf2f((unsigned short)v1[k]);
        if (cpt > 2) {
            const short8 v2 =
                *reinterpret_cast<const short8*>(p0 + 2 * PART_B + go);
#pragma unroll
            for (int k = 0; k < 8; ++k) s[k] += bf2f((unsigned short)v2[k]);
        }
        if (cpt > 3) {
            const short8 v3 =
                *reinterpret_cast<const short8*>(p0 + 3 * PART_B + go);
#pragma unroll
            for (int k = 0; k < 8; ++k) s[k] += bf2f((unsigned short)v3[k]);
        }
        const int rr = g >> 5;                   // 32 groups per 256-col row
        const int cc = (g & 31) * 8;
        float* dst = &C[(size_t)(row0 + rr) * NDIM + col0 + cc];
        *reinterpret_cast<f32x4*>(dst) = *reinterpret_cast<const f32x4*>(&s[0]);
        *reinterpret_cast<f32x4*>(dst + 4) =
            *reinterpret_cast<const f32x4*>(&s[4]);
    }
}

// ---------------- fallback (proven R3 kernel, no workspace) ----------------
#define FLSTR 80
#define NBLK 32
__device__ __forceinline__ int floff(int row, int kb) { return row * FLSTR + kb; }

__global__ __launch_bounds__(256) void trimm_fallback_kernel(
    const float* __restrict__ A, const float* __restrict__ B,
    float* __restrict__ C) {
    const int tid = threadIdx.x;
    const int id = blockIdx.x;
    int bi, bj;
    if (id >= 528) {
        int r = id - 528;
        int p = 1;
        while (r >= p) { r -= p; ++p; }
        bi = p; bj = r;
        const size_t base = (size_t)bi * 128 * NDIM + (size_t)bj * 128;
        const float4 z = make_float4(0.f, 0.f, 0.f, 0.f);
#pragma unroll
        for (int t = 0; t < 16; ++t) {
            const int f = tid + 256 * t;
            *reinterpret_cast<float4*>(
                &C[base + (size_t)(f >> 5) * NDIM + (f & 31) * 4]) = z;
        }
        return;
    }
    {
        int r = id, L = NBLK;
        while (r >= NBLK + 1 - L) { r -= NBLK + 1 - L; --L; }
        bi = r; bj = bi + L - 1;
    }
    const int row0 = bi * 128, col0 = bj * 128;
    __shared__ __align__(16) char lAs[128 * FLSTR];
    __shared__ __align__(16) char lBs[128 * FLSTR];
    f32x4 acc[4][4];
    const f32x4 fz = {0.f, 0.f, 0.f, 0.f};
#pragma unroll
    for (int m = 0; m < 4; ++m)
#pragma unroll
        for (int n = 0; n < 4; ++n) acc[m][n] = fz;
    const int wv = tid >> 6, wr = (wv >> 1) * 64, wc = (wv & 1) * 64;
    const int lane = tid & 63, fr = lane & 15, kb = (lane >> 4) * 16;
    const int bn = tid & 127, bkh = (tid >> 7) * 16;
    const int kendf = col0 + 128;
    for (int kt = row0; kt < kendf; kt += 32) {
        __syncthreads();
#pragma unroll
        for (int j = 0; j < 4; ++j) {
            const int f = tid + 256 * j;
            const int rr = f >> 3, kq = (f & 7) * 4;
            const float4 v = *reinterpret_cast<const float4*>(
                &A[(size_t)(row0 + rr) * NDIM + kt + kq]);
            uint2 w;
            w.x = pkbf(v.x, v.y); w.y = pkbf(v.z, v.w);
            *reinterpret_cast<uint2*>(lAs + floff(rr, kq * 2)) = w;
        }
        {
            float tv[16];
#pragma unroll
            for (int kk = 0; kk < 16; ++kk)
                tv[kk] = B[(size_t)(kt + bkh + kk) * NDIM + col0 + bn];
            uint4 w0, w1;
            w0.x = pkbf(tv[0], tv[1]);   w0.y = pkbf(tv[2], tv[3]);
            w0.z = pkbf(tv[4], tv[5]);   w0.w = pkbf(tv[6], tv[7]);
            w1.x = pkbf(tv[8], tv[9]);   w1.y = pkbf(tv[10], tv[11]);
            w1.z = pkbf(tv[12], tv[13]); w1.w = pkbf(tv[14], tv[15]);
            *reinterpret_cast<uint4*>(lBs + floff(bn, bkh * 2)) = w0;
            *reinterpret_cast<uint4*>(lBs + floff(bn, bkh * 2 + 16)) = w1;
        }
        __syncthreads();
        short8 af[4], bf[4];
#pragma unroll
        for (int m = 0; m < 4; ++m)
            af[m] = *reinterpret_cast<const short8*>(
                lAs + floff(wr + m * 16 + fr, kb));
#pragma unroll
        for (int n = 0; n < 4; ++n)
            bf[n] = *reinterpret_cast<const short8*>(
                lBs + floff(wc + n * 16 + fr, kb));
#pragma unroll
        for (int m = 0; m < 4; ++m)
#pragma unroll
            for (int n = 0; n < 4; ++n)
                acc[m][n] = __builtin_amdgcn_mfma_f32_16x16x32_bf16(
                    af[m], bf[n], acc[m][n], 0, 0, 0);
    }
#pragma unroll
    for (int m = 0; m < 4; ++m) {
        const int rbase = row0 + wr + m * 16 + (lane >> 4) * 4;
#pragma unroll
        for (int n = 0; n < 4; ++n) {
            const int col = col0 + wc + n * 16 + fr;
#pragma unroll
            for (int r = 0; r < 4; ++r) {
                const int row = rbase + r;
                C[(size_t)row * NDIM + col] = (row <= col) ? acc[m][n][r] : 0.f;
            }
        }
    }
}

extern "C" void kernel_launch(void* const* d_in, const int* in_sizes, int n_in,
                              void* d_out, int out_size, void* d_ws,
                              size_t ws_size, hipStream_t stream) {
    const float* A = (const float*)d_in[0];
    const float* B = (const float*)d_in[1];
    float* C = (float*)d_out;
    if (ws_size >= WS_NEED) {
        char* ws = (char*)d_ws;
        char* part = ws + POFF;
        prep_kernel<<<dim3(2 * NSUBT + 1), dim3(256), 0, stream>>>(A, B, ws);
        trimm256_kernel<<<dim3(NMAIN + NZERO), dim3(1024), 0, stream>>>(
            ws, C, part);
        reduce_kernel<<<dim3(NRED * 16), dim3(256), 0, stream>>>(part, C);
    } else {
        trimm_fallback_kernel<<<dim3(1024), dim3(256), 0, stream>>>(A, B, C);
    }
}

// Round 24
// 63.721 us; speedup vs baseline: 5.5920x; 1.0013x over previous
//
#include <hip/hip_runtime.h>
#include <hip/hip_bf16.h>

// C = triu( triu(A) @ triu(B) ), N=4096, fp32 in/out.  [R22 restore]
// Pass 1 (prep): convert fp32->bf16 into TILED FRAGMENT-ORDER 128x32 subtiles
// in d_ws + 8KB zero page.
// Pass 2 (main): 256x256 tiles; K split into <=36-step chunks -> 248 GEMM
// blocks (16 waves, 64x64/wave, 2x32KB double buffer, vmcnt(0)+barrier per
// step) + 496 appended blocks that zero the strictly-lower 128-tiles of C.
// L<=4 tiles: direct masked stores. L>=5: bf16 partials.
// Pass 3 (reduce): 78 tiles x 16 row-stripes = 1248 blocks.
// R23's phases+counted-vmcnt variant RACED (post-timing divergence) -> this
// is the fastest PROVEN state (63.8us).

#define NDIM 4096
#define SUBT_B 8192                        // one 128x32 bf16 subtile
#define NSUBT 2112                         // packed subtiles per matrix
#define WS_A ((size_t)NSUBT * SUBT_B)      // 17,301,504
#define WS_TOTAL (2 * WS_A)                // 34,603,008
#define ZOFF WS_TOTAL                      // 8KB zero page
#define POFF (WS_TOTAL + 8192)             // bf16 partial region
#define NSLOT 190                          // split chunk-blocks
#define PART_B 131072                      // 256x256 bf16 partial tile
#define WS_NEED (POFF + (size_t)NSLOT * PART_B)   // 59,514,880
#define NZERO 496                          // strictly-lower 128x128 tiles
#define NMAIN 248
#define NRED 78
#define CS 36                              // steps per chunk (even)

typedef __attribute__((ext_vector_type(8))) short short8;
typedef __attribute__((ext_vector_type(4))) float f32x4;

__device__ __forceinline__ unsigned pkbf(float a, float b) {
    __hip_bfloat162 h = __float22bfloat162_rn(make_float2(a, b));
    unsigned r;
    __builtin_memcpy(&r, &h, sizeof(r));
    return r;
}

__device__ __forceinline__ float bf2f(unsigned short us) {
    const unsigned u = ((unsigned)us) << 16;
    float f;
    __builtin_memcpy(&f, &u, 4);
    return f;
}

__device__ __forceinline__ void gll16(const void* g, void* l) {
    __builtin_amdgcn_global_load_lds(
        (const __attribute__((address_space(1))) unsigned int*)g,
        (__attribute__((address_space(3))) unsigned int*)l, 16, 0, 0);
}

__device__ __forceinline__ int offA(int p) { return 130 * p - 2 * p * p; }
__device__ __forceinline__ int offB(int q) { return 2 * q * (q + 1); }

// ---------------- pass 1: convert/tile A,B + zero page ---------------------
__global__ __launch_bounds__(256) void prep_kernel(
    const float* __restrict__ A, const float* __restrict__ B,
    char* __restrict__ ws) {
    const int t = threadIdx.x;
    int b = blockIdx.x;

    if (b < NSUBT) {  // ---- A subtile: [row][k] fp32 -> [g][row][16B] bf16 ----
        int bi = 0, rem = b;
        while (rem >= 128 - 4 * bi) { rem -= 128 - 4 * bi; ++bi; }
        const int kt32 = 4 * bi + rem;

        __shared__ __align__(16) char lsub[SUBT_B];
        const float* src = A + (size_t)(bi * 128) * NDIM + kt32 * 32;
#pragma unroll
        for (int j = 0; j < 4; ++j) {
            const int s4 = t + 256 * j;
            const int row = s4 >> 3;
            const int kf = (s4 & 7) * 4;
            const float4 v =
                *reinterpret_cast<const float4*>(src + (size_t)row * NDIM + kf);
            uint2 w;
            w.x = pkbf(v.x, v.y);
            w.y = pkbf(v.z, v.w);
            *reinterpret_cast<uint2*>(lsub + (kf >> 3) * 2048 + row * 16 +
                                      (kf & 4) * 2) = w;
        }
        __syncthreads();
        char* dst = ws + (size_t)b * SUBT_B;
#pragma unroll
        for (int j = 0; j < 2; ++j) {
            const int d = t + 256 * j;
            *reinterpret_cast<uint4*>(dst + d * 16) =
                *reinterpret_cast<const uint4*>(lsub + d * 16);
        }
        return;
    }
    b -= NSUBT;

    if (b < NSUBT) {  // ---- B subtile: [k][col] fp32 -> [g][col][16B] bf16 ----
        int bj = 0, rem = b;
        while (rem >= 4 * (bj + 1)) { rem -= 4 * (bj + 1); ++bj; }
        const int kt32 = rem;

        const int c = t & 127;
        const int kq = (t >> 7) * 16;
        const float* src = B + (size_t)(kt32 * 32 + kq) * NDIM + bj * 128 + c;
        float v[16];
#pragma unroll
        for (int i = 0; i < 16; ++i) v[i] = src[(size_t)i * NDIM];

        uint4 w0, w1;
        w0.x = pkbf(v[0], v[1]);   w0.y = pkbf(v[2], v[3]);
        w0.z = pkbf(v[4], v[5]);   w0.w = pkbf(v[6], v[7]);
        w1.x = pkbf(v[8], v[9]);   w1.y = pkbf(v[10], v[11]);
        w1.z = pkbf(v[12], v[13]); w1.w = pkbf(v[14], v[15]);

        char* dst = ws + WS_A + (size_t)b * SUBT_B + c * 16;
        const int g0 = kq >> 3;
        *reinterpret_cast<uint4*>(dst + g0 * 2048) = w0;
        *reinterpret_cast<uint4*>(dst + (g0 + 1) * 2048) = w1;
        return;
    }

    {  // ---- 8KB zero page ----
        uint4* zp = reinterpret_cast<uint4*>(ws + ZOFF);
        const uint4 z = {0u, 0u, 0u, 0u};
        zp[t] = z;
        zp[t + 256] = z;
    }
}

// ------- pass 2: 256x256 MFMA GEMM (16 waves) + lower-tile zero blocks -----
__global__ __launch_bounds__(1024) void trimm256_kernel(
    const char* __restrict__ ws, float* __restrict__ C,
    char* __restrict__ part) {
    const int tid = threadIdx.x;

    if (blockIdx.x >= NMAIN) {
        // ---- zero one strictly-lower 128x128 tile of C ----
        int r = blockIdx.x - NMAIN, p = 1;
        while (r >= p) { r -= p; ++p; }
        const int zbi = p, zbj = r;        // zbj < zbi
        const size_t base = (size_t)zbi * 128 * NDIM + (size_t)zbj * 128;
        const float4 z = make_float4(0.f, 0.f, 0.f, 0.f);
#pragma unroll
        for (int j = 0; j < 4; ++j) {
            const int f = tid + 1024 * j;  // 0..4095 float4 chunks
            *reinterpret_cast<float4*>(
                &C[base + (size_t)(f >> 5) * NDIM + (f & 31) * 4]) = z;
        }
        return;
    }

    // decode (L desc, bi asc, ch asc): split chunks (L>=5) are ids 0..189
    int bi, bj, ch, cpt;
    {
        int r = blockIdx.x;
        int L = 16;
        for (;; --L) {
            cpt = (8 * L + CS - 1) / CS;
            const int cnt = (17 - L) * cpt;
            if (r < cnt) { bi = r / cpt; ch = r % cpt; break; }
            r -= cnt;
        }
        bj = bi + L - 1;
    }

    const int row0 = bi * 256;
    const int col0 = bj * 256;
    const int ntt = 8 * (bj - bi + 1);           // total steps for the tile
    const int g0 = ch * CS;
    const int nt = min(CS, ntt - g0);            // 4..36 steps this chunk
    const bool direct = (cpt == 1);

    // subtile streams indexed by GLOBAL step g; zero page at triu edges
    const char* srcA0 = ws + (size_t)(offA(2 * bi)) * SUBT_B;
    const char* srcA1 = ws + (size_t)(offA(2 * bi + 1) - 4) * SUBT_B;
    const char* srcB0 = ws + WS_A + (size_t)(offB(2 * bj) + 8 * bi) * SUBT_B;
    const char* srcB1 = ws + WS_A + (size_t)(offB(2 * bj + 1) + 8 * bi) * SUBT_B;
    const char* zpage = ws + ZOFF;

    __shared__ __align__(16) char lds[2][4][SUBT_B];   // 64 KB

    f32x4 acc[4][4];
    const f32x4 fz = {0.f, 0.f, 0.f, 0.f};
#pragma unroll
    for (int m = 0; m < 4; ++m)
#pragma unroll
        for (int n = 0; n < 4; ++n) acc[m][n] = fz;

    const int wv = tid >> 6;            // 0..15
    const int wvM = wv >> 2;            // 0..3: 64-row band
    const int wvN = wv & 3;             // 0..3: 64-col band
    const int lane = tid & 63;
    const int fr = lane & 15;
    const int gof = (lane >> 4) * 2048;
    const int arb = (wvM & 1) * 64;     // row base within A subtile
    const int cbase = (wvN & 1) * 64;   // col base within B subtile
    const int soff = (wv & 7) * 1024;   // staging slice offset

    auto stage = [&](int buf, int g) {  // 2 gll16 per thread
#pragma unroll
        for (int q = 0; q < 2; ++q) {
            const int s = q * 2 + (wv >> 3);     // wave-uniform subtile id
            const char* src;
            if (s == 0)      src = srcA0 + (size_t)g * SUBT_B;
            else if (s == 1) src = (g >= 4) ? srcA1 + (size_t)g * SUBT_B : zpage;
            else if (s == 2) src = (g < ntt - 4) ? srcB0 + (size_t)g * SUBT_B : zpage;
            else             src = srcB1 + (size_t)g * SUBT_B;
            gll16(src + soff + lane * 16, &lds[buf][s][0] + soff);
        }
    };
    auto compute = [&](int buf) {
        const char* A_ = &lds[buf][wvM >> 1][0];
        const char* B_ = &lds[buf][2 + (wvN >> 1)][0];
        short8 af[4], bf[4];
#pragma unroll
        for (int m = 0; m < 4; ++m)
            af[m] = *reinterpret_cast<const short8*>(
                A_ + gof + (arb + m * 16 + fr) * 16);
#pragma unroll
        for (int n = 0; n < 4; ++n)
            bf[n] = *reinterpret_cast<const short8*>(
                B_ + gof + (cbase + n * 16 + fr) * 16);
        __builtin_amdgcn_s_setprio(1);
#pragma unroll
        for (int m = 0; m < 4; ++m)
#pragma unroll
            for (int n = 0; n < 4; ++n)
                acc[m][n] = __builtin_amdgcn_mfma_f32_16x16x32_bf16(
                    af[m], bf[n], acc[m][n], 0, 0, 0);
        __builtin_amdgcn_s_setprio(0);
    };

    // ---- 2x32KB single-step double-buffer ----
    stage(0, g0);
    for (int t = 0; t < nt; ++t) {
        asm volatile("s_waitcnt vmcnt(0)" ::: "memory");
        __builtin_amdgcn_s_barrier();
        if (t + 1 < nt) stage((t + 1) & 1, g0 + t + 1);
        compute(t & 1);
    }

    if (direct) {
        // ---- direct masked store (tile may touch the diagonal) ----
#pragma unroll
        for (int m = 0; m < 4; ++m) {
            const int rbase = row0 + wvM * 64 + m * 16 + (lane >> 4) * 4;
#pragma unroll
            for (int n = 0; n < 4; ++n) {
                const int col = col0 + wvN * 64 + n * 16 + fr;
#pragma unroll
                for (int r = 0; r < 4; ++r) {
                    const int row = rbase + r;
                    C[(size_t)row * NDIM + col] =
                        (row <= col) ? acc[m][n][r] : 0.f;
                }
            }
        }
    } else {
        // ---- bf16 partial tile, row-major [256][256], slot = blockIdx ----
        char* po = part + (size_t)blockIdx.x * PART_B;
#pragma unroll
        for (int m = 0; m < 4; ++m) {
            const int rl = wvM * 64 + m * 16 + (lane >> 4) * 4;
#pragma unroll
            for (int n = 0; n < 4; ++n) {
                const int cl = wvN * 64 + n * 16 + fr;
#pragma unroll
                for (int r = 0; r < 4; ++r) {
                    const unsigned short us =
                        (unsigned short)(pkbf(acc[m][n][r], 0.f) & 0xffffu);
                    *reinterpret_cast<unsigned short*>(
                        po + (size_t)((rl + r) * 256 + cl) * 2) = us;
                }
            }
        }
    }
}

// ------- pass 3: sum bf16 partials -> C (78 tiles x 16 stripes) ------------
__global__ __launch_bounds__(256) void reduce_kernel(
    const char* __restrict__ part, float* __restrict__ C) {
    const int t = threadIdx.x;
    const int tile = blockIdx.x >> 4;            // 0..77
    const int stripe = blockIdx.x & 15;          // 16 rows each
    int bi, L, slot0, cpt;
    {
        int r = tile, sbase = 0;
        for (L = 16;; --L) {
            cpt = (8 * L + CS - 1) / CS;
            const int cnt = 17 - L;              // tiles at this L (all split)
            if (r < cnt) { bi = r; slot0 = sbase + r * cpt; break; }
            sbase += cnt * cpt;
            r -= cnt;
        }
    }
    const int bj = bi + L - 1;                   // L>=5 -> strictly upper
    const int row0 = bi * 256;
    const int col0 = bj * 256;

    const char* p0 = part + (size_t)slot0 * PART_B;
#pragma unroll
    for (int j = 0; j < 2; ++j) {
        const int g = stripe * 512 + j * 256 + t;   // 8-elem group 0..8191
        const size_t go = (size_t)g * 16;
        float s[8];
        const short8 v0 = *reinterpret_cast<const short8*>(p0 + go);
        const short8 v1 = *reinterpret_cast<const short8*>(p0 + PART_B + go);
#pragma unroll
        for (int k = 0; k < 8; ++k)
            s[k] = bf2f((unsigned short)v0[k]) + bf2f((unsigned short)v1[k]);
        if (cpt > 2) {
            const short8 v2 =
                *reinterpret_cast<const short8*>(p0 + 2 * PART_B + go);
#pragma unroll
            for (int k = 0; k < 8; ++k) s[k] += bf2f((unsigned short)v2[k]);
        }
        if (cpt > 3) {
            const short8 v3 =
                *reinterpret_cast<const short8*>(p0 + 3 * PART_B + go);
#pragma unroll
            for (int k = 0; k < 8; ++k) s[k] += bf2f((unsigned short)v3[k]);
        }
        const int rr = g >> 5;                   // 32 groups per 256-col row
        const int cc = (g & 31) * 8;
        float* dst = &C[(size_t)(row0 + rr) * NDIM + col0 + cc];
        *reinterpret_cast<f32x4*>(dst) = *reinterpret_cast<const f32x4*>(&s[0]);
        *reinterpret_cast<f32x4*>(dst + 4) =
            *reinterpret_cast<const f32x4*>(&s[4]);
    }
}

// ---------------- fallback (proven R3 kernel, no workspace) ----------------
#define FLSTR 80
#define NBLK 32
__device__ __forceinline__ int floff(int row, int kb) { return row * FLSTR + kb; }

__global__ __launch_bounds__(256) void trimm_fallback_kernel(
    const float* __restrict__ A, const float* __restrict__ B,
    float* __restrict__ C) {
    const int tid = threadIdx.x;
    const int id = blockIdx.x;
    int bi, bj;
    if (id >= 528) {
        int r = id - 528;
        int p = 1;
        while (r >= p) { r -= p; ++p; }
        bi = p; bj = r;
        const size_t base = (size_t)bi * 128 * NDIM + (size_t)bj * 128;
        const float4 z = make_float4(0.f, 0.f, 0.f, 0.f);
#pragma unroll
        for (int t = 0; t < 16; ++t) {
            const int f = tid + 256 * t;
            *reinterpret_cast<float4*>(
                &C[base + (size_t)(f >> 5) * NDIM + (f & 31) * 4]) = z;
        }
        return;
    }
    {
        int r = id, L = NBLK;
        while (r >= NBLK + 1 - L) { r -= NBLK + 1 - L; --L; }
        bi = r; bj = bi + L - 1;
    }
    const int row0 = bi * 128, col0 = bj * 128;
    __shared__ __align__(16) char lAs[128 * FLSTR];
    __shared__ __align__(16) char lBs[128 * FLSTR];
    f32x4 acc[4][4];
    const f32x4 fz = {0.f, 0.f, 0.f, 0.f};
#pragma unroll
    for (int m = 0; m < 4; ++m)
#pragma unroll
        for (int n = 0; n < 4; ++n) acc[m][n] = fz;
    const int wv = tid >> 6, wr = (wv >> 1) * 64, wc = (wv & 1) * 64;
    const int lane = tid & 63, fr = lane & 15, kb = (lane >> 4) * 16;
    const int bn = tid & 127, bkh = (tid >> 7) * 16;
    const int kendf = col0 + 128;
    for (int kt = row0; kt < kendf; kt += 32) {
        __syncthreads();
#pragma unroll
        for (int j = 0; j < 4; ++j) {
            const int f = tid + 256 * j;
            const int rr = f >> 3, kq = (f & 7) * 4;
            const float4 v = *reinterpret_cast<const float4*>(
                &A[(size_t)(row0 + rr) * NDIM + kt + kq]);
            uint2 w;
            w.x = pkbf(v.x, v.y); w.y = pkbf(v.z, v.w);
            *reinterpret_cast<uint2*>(lAs + floff(rr, kq * 2)) = w;
        }
        {
            float tv[16];
#pragma unroll
            for (int kk = 0; kk < 16; ++kk)
                tv[kk] = B[(size_t)(kt + bkh + kk) * NDIM + col0 + bn];
            uint4 w0, w1;
            w0.x = pkbf(tv[0], tv[1]);   w0.y = pkbf(tv[2], tv[3]);
            w0.z = pkbf(tv[4], tv[5]);   w0.w = pkbf(tv[6], tv[7]);
            w1.x = pkbf(tv[8], tv[9]);   w1.y = pkbf(tv[10], tv[11]);
            w1.z = pkbf(tv[12], tv[13]); w1.w = pkbf(tv[14], tv[15]);
            *reinterpret_cast<uint4*>(lBs + floff(bn, bkh * 2)) = w0;
            *reinterpret_cast<uint4*>(lBs + floff(bn, bkh * 2 + 16)) = w1;
        }
        __syncthreads();
        short8 af[4], bf[4];
#pragma unroll
        for (int m = 0; m < 4; ++m)
            af[m] = *reinterpret_cast<const short8*>(
                lAs + floff(wr + m * 16 + fr, kb));
#pragma unroll
        for (int n = 0; n < 4; ++n)
            bf[n] = *reinterpret_cast<const short8*>(
                lBs + floff(wc + n * 16 + fr, kb));
#pragma unroll
        for (int m = 0; m < 4; ++m)
#pragma unroll
            for (int n = 0; n < 4; ++n)
                acc[m][n] = __builtin_amdgcn_mfma_f32_16x16x32_bf16(
                    af[m], bf[n], acc[m][n], 0, 0, 0);
    }
#pragma unroll
    for (int m = 0; m < 4; ++m) {
        const int rbase = row0 + wr + m * 16 + (lane >> 4) * 4;
#pragma unroll
        for (int n = 0; n < 4; ++n) {
            const int col = col0 + wc + n * 16 + fr;
#pragma unroll
            for (int r = 0; r < 4; ++r) {
                const int row = rbase + r;
                C[(size_t)row * NDIM + col] = (row <= col) ? acc[m][n][r] : 0.f;
            }
        }
    }
}

extern "C" void kernel_launch(void* const* d_in, const int* in_sizes, int n_in,
                              void* d_out, int out_size, void* d_ws,
                              size_t ws_size, hipStream_t stream) {
    const float* A = (const float*)d_in[0];
    const float* B = (const float*)d_in[1];
    float* C = (float*)d_out;
    if (ws_size >= WS_NEED) {
        char* ws = (char*)d_ws;
        char* part = ws + POFF;
        prep_kernel<<<dim3(2 * NSUBT + 1), dim3(256), 0, stream>>>(A, B, ws);
        trimm256_kernel<<<dim3(NMAIN + NZERO), dim3(1024), 0, stream>>>(
            ws, C, part);
        reduce_kernel<<<dim3(NRED * 16), dim3(256), 0, stream>>>(part, C);
    } else {
        trimm_fallback_kernel<<<dim3(1024), dim3(256), 0, stream>>>(A, B, C);
    }
}